// Round 4
// baseline (234.824 us; speedup 1.0000x reference)
//
#include <hip/hip_runtime.h>
#include <hip/hip_bf16.h>

// Problem constants (SelfAttention: B=4, S=2048, E=1024, H=16, D=64)
#define B_  4
#define S_  2048
#define E_  1024
#define H_  16
#define D_  64
#define M_  (B_*S_)     // 8192
#define N3_ (3*E_)      // 3072

typedef __bf16 bf16;
typedef bf16  bf16x4 __attribute__((ext_vector_type(4)));
typedef bf16  bf16x8 __attribute__((ext_vector_type(8)));
typedef float f32x4  __attribute__((ext_vector_type(4)));

#define SC2 0.18033688011112043f   // (1/sqrt(64)) * log2(e), folded into Q

__device__ __forceinline__ f32x4 mfma16(bf16x8 a, bf16x8 b, f32x4 c) {
    return __builtin_amdgcn_mfma_f32_16x16x32_bf16(a, b, c, 0, 0, 0);
}

typedef const __attribute__((address_space(1))) void* gas_t;
typedef __attribute__((address_space(3))) void* las_t;
__device__ __forceinline__ void gl_lds16(const void* g, void* l) {
    __builtin_amdgcn_global_load_lds((gas_t)g, (las_t)l, 16, 0, 0);
}

// s_waitcnt imm = (vm_hi<<14)|(lgkm<<8)|(exp<<4)|vm_lo ; lgkm=15,exp=7 = no-wait
#define WAITCNT_VM4() __builtin_amdgcn_s_waitcnt(0x0F74)   // vmcnt(4) only
#define WAITCNT_VM2() __builtin_amdgcn_s_waitcnt(0x0F72)   // vmcnt(2) only
#define WAITCNT_VM0() __builtin_amdgcn_s_waitcnt(0x0F70)   // vmcnt(0) only

// ---------------------------------------------------------------- fp32->bf16 (all 3 tensors, one launch)
__global__ __launch_bounds__(256) void cvt_all(const float* __restrict__ x,
                                               const float* __restrict__ w_in,
                                               const float* __restrict__ w_out,
                                               bf16* __restrict__ Xbf,
                                               bf16* __restrict__ Wqkv,
                                               bf16* __restrict__ Wo) {
    const int n1 = M_ * E_ / 4, n2 = N3_ * E_ / 4, n3 = E_ * E_ / 4;
    int i = blockIdx.x * blockDim.x + threadIdx.x;
    const float* src; bf16* dst; int j;
    if (i < n1)           { src = x;     dst = Xbf;  j = i; }
    else if (i < n1 + n2) { src = w_in;  dst = Wqkv; j = i - n1; }
    else if (i < n1 + n2 + n3) { src = w_out; dst = Wo; j = i - n1 - n2; }
    else return;
    float4 v = *(const float4*)(src + (size_t)j * 4);
    bf16x4 o;
    o[0] = (bf16)v.x; o[1] = (bf16)v.y; o[2] = (bf16)v.z; o[3] = (bf16)v.w;
    *(bf16x4*)(dst + (size_t)j * 4) = o;
}

// ---------------------------------------------------------------- QKV GEMM (round-0 proven version, 65.0us)
// 128x128 tile, BK=64 (XOR-swizzled LDS), 4 waves 2x2, each 64x64 (4x4 frags).
// Q/K blocks (n0<2048): C = X·W^T, scatter to Q/K [B,H,S,D]; Q pre-scaled SC2.
// V blocks (n0>=2048): operands swapped (C = W·X^T) so C rows = d, cols = s;
// epilogue writes Vt[bh][d][s] directly — the V transpose is free.
// History: R1 triple-buffer counted-vmcnt NEUTRAL (66.0); R3 confirmed this
// version at 65.0. 256²/256x128 8-phase rejected: at K=1024 the 8-phase gain
// (m248: ~1.1-1.3x) x grid-round efficiency loss = wash or worse.
__global__ __launch_bounds__(256) void gemm_qkv(const bf16* __restrict__ X,
                                                const bf16* __restrict__ W,
                                                const float* __restrict__ bias,
                                                bf16* __restrict__ QKV,
                                                bf16* __restrict__ Vt) {
    __shared__ __align__(16) bf16 As[128 * 64];
    __shared__ __align__(16) bf16 Bs[128 * 64];
    const int t = threadIdx.x;
    const int wav = t >> 6, lane = t & 63, quad = lane >> 4, l15 = lane & 15;
    const int m0 = blockIdx.y * 128, n0 = blockIdx.x * 128;
    const int wr = (wav >> 1) * 64, wc = (wav & 1) * 64;
    const int srow = t >> 3;
    const int swz  = ((t & 7) ^ (srow & 7)) * 8;
    const bool isV = (n0 >= 2 * E_);

    const bf16* Ablk = X + (size_t)m0 * E_;
    const bf16* Bblk = W + (size_t)n0 * E_;
    f32x4 acc[4][4] = {};

    for (int kk = 0; kk < E_; kk += 64) {
        __syncthreads();
        #pragma unroll
        for (int ps = 0; ps < 4; ++ps) {
            gl_lds16(Ablk + (size_t)(srow + ps * 32) * E_ + kk + swz, As + (size_t)(t + ps * 256) * 8);
            gl_lds16(Bblk + (size_t)(srow + ps * 32) * E_ + kk + swz, Bs + (size_t)(t + ps * 256) * 8);
        }
        __syncthreads();
        #pragma unroll
        for (int ks = 0; ks < 2; ++ks) {
            bf16x8 af[4], bw[4];
            #pragma unroll
            for (int i = 0; i < 4; ++i) {
                const int ra = wr + i * 16 + l15;
                const int rb = wc + i * 16 + l15;
                const int cx = ((ks * 4 + quad) ^ (l15 & 7)) * 8;
                af[i] = *(const bf16x8*)&As[ra * 64 + cx];
                bw[i] = *(const bf16x8*)&Bs[rb * 64 + cx];
            }
            if (!isV) {
                #pragma unroll
                for (int i = 0; i < 4; ++i)
                    #pragma unroll
                    for (int j = 0; j < 4; ++j)
                        acc[i][j] = mfma16(af[i], bw[j], acc[i][j]);
            } else {
                #pragma unroll
                for (int i = 0; i < 4; ++i)
                    #pragma unroll
                    for (int j = 0; j < 4; ++j)
                        acc[i][j] = mfma16(bw[i], af[j], acc[i][j]);
            }
        }
    }
    if (!isV) {
        #pragma unroll
        for (int i = 0; i < 4; ++i)
            #pragma unroll
            for (int j = 0; j < 4; ++j)
                #pragma unroll
                for (int r = 0; r < 4; ++r) {
                    int mg = m0 + wr + i * 16 + quad * 4 + r;
                    int ng = n0 + wc + j * 16 + l15;
                    float v = acc[i][j][r] + bias[ng];
                    int which = ng >> 10, rem = ng & 1023;
                    if (which == 0) v *= SC2;
                    int h = rem >> 6, d = rem & 63;
                    int b = mg >> 11, s = mg & 2047;
                    QKV[(size_t)which * (B_ * H_ * S_ * D_) +
                        (((size_t)(b * H_ + h) * S_ + s) * D_ + d)] = (bf16)v;
                }
    } else {
        #pragma unroll
        for (int i = 0; i < 4; ++i)
            #pragma unroll
            for (int j = 0; j < 4; ++j)
                #pragma unroll
                for (int r = 0; r < 4; ++r) {
                    int ng = n0 + wc + i * 16 + quad * 4 + r;
                    int mg = m0 + wr + j * 16 + l15;
                    float v = acc[i][j][r] + bias[ng];
                    int rem = ng & 1023;
                    int h = rem >> 6, d = rem & 63;
                    int b = mg >> 11, s = mg & 2047;
                    Vt[(((size_t)(b * H_ + h) * D_ + d) * S_) + s] = (bf16)v;
                }
    }
}

// ---------------------------------------------------------------- attention
// R4: R0 structure EXACTLY (16 q/wave, 8-wave blocks over 128 q rows, 512
// blocks, KT=64 — R2/R3 post-mortems: both restructures lost; this structure
// is the local optimum). Three stall-removal changes inside it:
//  1) TRIPLE-buffered K/V (LDS 48->64 KB, still 2 blocks/CU): stage tile
//     it+2, head wait vmcnt(4) -> DMAs get ~2 iterations to land instead
//     of ~1 (L2 latency 200-450cy vs ~500cy/iter was marginal).
//  2) s_setprio(1) around QK and PV MFMA clusters (m191: +4-7% attn with
//     independent blocks per CU — we have 2).
//  3) Wave-uniform compute-skip of fully-masked tiles (barriers/staging
//     kept -> no deadlock; exp2(-3e38)=0 so numerically identical).
// Uniform-work causal pairing over 16 q-tiles of 128 (p & 15-p).
// LDS = 3*8K (K) + 3*8K (V) + 16K (P) = 64 KB -> 2 blocks/CU.
__global__ __launch_bounds__(512, 4) void attn8(const bf16* __restrict__ Q,
                                                const bf16* __restrict__ K,
                                                const bf16* __restrict__ Vt,
                                                bf16* __restrict__ O) {
    __shared__ __align__(16) bf16 Ks[3][64 * 64];      // [buf][key][d]   (XOR-swizzled chunks)
    __shared__ __align__(16) bf16 Vs[3][64 * 64];      // [buf][d][key]   (XOR-swizzled chunks)
    __shared__ __align__(16) bf16 Ps[8][16 * 64];      // per-wave P, XOR-swizzled chunks

    const int t = threadIdx.x;
    const int wav = t >> 6, lane = t & 63, quad = lane >> 4, l15 = lane & 15;
    const int p  = blockIdx.x >> 6;      // pair index 0..7
    const int bh = blockIdx.x & 63;

    const bf16* Qb = Q  + (size_t)bh * S_ * D_;
    const bf16* Kb = K  + (size_t)bh * S_ * D_;
    const bf16* Vb = Vt + (size_t)bh * (size_t)D_ * S_;   // [d][s]

    const int srow = t >> 3;                      // staging row 0..63
    const int swz  = ((t & 7) ^ (srow & 7)) * 8;  // swizzled global chunk offset
    bf16* Pw = &Ps[wav][0];
    const int pswz = l15 & 7;                     // P chunk swizzle key

    const int b = bh >> 4, h = bh & 15;

    #pragma unroll 1
    for (int phase = 0; phase < 2; ++phase) {
        const int qb  = phase ? (15 - p) : p;     // q-tile of 128
        const int q0w = qb * 128 + wav * 16;
        const int qg  = q0w + l15;
        const int niter = 2 * qb + 2;

        __builtin_amdgcn_s_barrier();   // prior phase's buf reads complete
        // preload tiles 0,1 -> buf 0,1 (4 DMAs/thread)
        gl_lds16(Kb + (size_t)srow * D_ + swz,        &Ks[0][(size_t)t * 8]);
        gl_lds16(Vb + (size_t)srow * S_ + swz,        &Vs[0][(size_t)t * 8]);
        gl_lds16(Kb + (size_t)(64 + srow) * D_ + swz, &Ks[1][(size_t)t * 8]);
        gl_lds16(Vb + (size_t)srow * S_ + 64 + swz,   &Vs[1][(size_t)t * 8]);

        bf16x8 qf0 = *(const bf16x8*)&Qb[(size_t)(q0w + l15) * D_ + quad * 8];
        bf16x8 qf1 = *(const bf16x8*)&Qb[(size_t)(q0w + l15) * D_ + 32 + quad * 8];

        f32x4 oacc[4] = {};
        f32x4 psum = {0.f, 0.f, 0.f, 0.f};   // per-lane partial row sums (by r)

        #pragma unroll 1
        for (int it = 0; it < niter; ++it) {
            const int key0 = it * 64;
            const int cur = it % 3;
            const bf16* Kc = &Ks[cur][0];
            const bf16* Vc = &Vs[cur][0];

            // all waves done reading buf[(it+2)%3] (its last read was iter it-1)
            __builtin_amdgcn_s_barrier();
            if (it + 2 < niter) {                  // issue tile it+2 -> buf[(it+2)%3]
                const int kn = key0 + 128;
                const int nb = (it + 2) % 3;
                gl_lds16(Kb + (size_t)(kn + srow) * D_ + swz, &Ks[nb][(size_t)t * 8]);
                gl_lds16(Vb + (size_t)srow * S_ + kn + swz,   &Vs[nb][(size_t)t * 8]);
                WAITCNT_VM4();                     // tiles it+1, it+2 stay in flight
            } else if (it + 1 < niter) {
                WAITCNT_VM2();                     // tile it+1 stays in flight
            } else {
                WAITCNT_VM0();
            }
            __builtin_amdgcn_s_barrier();          // tile it visible to all waves

            // compute-skip: tile fully masked for this wave (keys all > its qs)
            if (key0 > q0w + 15) continue;         // wave-uniform; barriers above

            // --- QK^T -> S^T tiles (rows=key, cols=q); Q pre-scaled
            f32x4 sacc[4];
            __builtin_amdgcn_s_setprio(1);
            #pragma unroll
            for (int mt = 0; mt < 4; ++mt) {
                const int krow = mt * 16 + l15;
                const int sw = krow & 7;
                bf16x8 kf0 = *(const bf16x8*)&Kc[krow * 64 + ((quad ^ sw) * 8)];
                bf16x8 kf1 = *(const bf16x8*)&Kc[krow * 64 + (((4 + quad) ^ sw) * 8)];
                f32x4 a = {};
                a = mfma16(kf0, qf0, a);
                a = mfma16(kf1, qf1, a);
                sacc[mt] = a;
            }
            __builtin_amdgcn_s_setprio(0);

            // --- causal mask (diagonal tiles only)
            #pragma unroll
            for (int mt = 0; mt < 4; ++mt) {
                if (key0 + mt * 16 + 15 > q0w) {   // wave-uniform branch
                    #pragma unroll
                    for (int r = 0; r < 4; ++r) {
                        int key = key0 + mt * 16 + quad * 4 + r;
                        sacc[mt][r] = (key > qg) ? -3e38f : sacc[mt][r];
                    }
                }
            }

            // --- P = exp2(S) (no max-sub; lane-local), accumulate row sums,
            //     pack to bf16, write to per-wave swizzled P buffer
            #pragma unroll
            for (int mt = 0; mt < 4; ++mt) {
                bf16x4 pk;
                #pragma unroll
                for (int r = 0; r < 4; ++r) {
                    float pv = __builtin_amdgcn_exp2f(sacc[mt][r]);
                    psum[r] += pv;
                    pk[r] = (bf16)pv;
                }
                const int pc = ((mt * 2 + (quad >> 1)) ^ pswz) * 8 + (quad & 1) * 4;
                *(bf16x4*)&Pw[l15 * 64 + pc] = pk;
            }

            // --- PV: a = P rows (swizzled b128), b = Vt rows (swizzled b128)
            bf16x8 pf0 = *(const bf16x8*)&Pw[l15 * 64 + ((quad ^ pswz) * 8)];
            bf16x8 pf1 = *(const bf16x8*)&Pw[l15 * 64 + (((4 + quad) ^ pswz) * 8)];
            __builtin_amdgcn_s_setprio(1);
            #pragma unroll
            for (int nt = 0; nt < 4; ++nt) {
                const int vrow = nt * 16 + l15;
                const int sw = vrow & 7;
                bf16x8 vf0 = *(const bf16x8*)&Vc[vrow * 64 + ((quad ^ sw) * 8)];
                bf16x8 vf1 = *(const bf16x8*)&Vc[vrow * 64 + (((4 + quad) ^ sw) * 8)];
                oacc[nt] = mfma16(pf0, vf0, oacc[nt]);
                oacc[nt] = mfma16(pf1, vf1, oacc[nt]);
            }
            __builtin_amdgcn_s_setprio(0);
        }

        // --- deferred softmax denominator: one cross-quad reduction per phase
        float rsum = psum[0] + psum[1] + psum[2] + psum[3];
        rsum += __shfl_xor(rsum, 16);
        rsum += __shfl_xor(rsum, 32);
        const float linv = 1.0f / rsum;

        // --- phase epilogue: O[b, q, h*64 + d] = oacc / l
        #pragma unroll
        for (int rr = 0; rr < 4; ++rr) {
            float li = __shfl(linv, quad * 4 + rr);
            const int q = q0w + quad * 4 + rr;
            #pragma unroll
            for (int nt = 0; nt < 4; ++nt)
                O[((size_t)b * S_ + q) * E_ + h * D_ + nt * 16 + l15] =
                    (bf16)(oacc[nt][rr] * li);
        }
    }
}

// ---------------------------------------------------------------- out GEMM (R1 pipelined version, proven -4.6us vs R0)
// 256x128 tile, BK=64, 8 waves (4M x 2N). Triple-buffered LDS, counted
// vmcnt(6) head-of-window, setprio around MFMA clusters. 256 blocks = 1
// exact round of 256 CUs.
#define STG_A(dst, kk, ps) gl_lds16(Ablk + (size_t)(srow + (ps)*64)*E_ + (kk) + swz, (dst) + (size_t)(t + (ps)*512)*8)
#define STG_B(dst, kk, ps) gl_lds16(Bblk + (size_t)(srow + (ps)*64)*E_ + (kk) + swz, (dst) + (size_t)(t + (ps)*512)*8)
#define LDF(base, row, ks) (*(const bf16x8*)&(base)[(row)*64 + ((((ks)*4 + quad) ^ ((row)&7))*8)])

__global__ __launch_bounds__(512, 2) void gemm_out(const bf16* __restrict__ A,
                                                   const bf16* __restrict__ W,
                                                   const float* __restrict__ bias,
                                                   float* __restrict__ out) {
    __shared__ __align__(16) bf16 As[3][256 * 64];
    __shared__ __align__(16) bf16 Bs[3][128 * 64];
    const int t = threadIdx.x;
    const int wav = t >> 6, lane = t & 63, quad = lane >> 4, l15 = lane & 15;
    const int m0 = blockIdx.y * 256, n0 = blockIdx.x * 128;
    const int wro = (wav >> 1) * 64, wco = (wav & 1) * 64;
    const int srow = t >> 3;
    const int swz  = ((t & 7) ^ (srow & 7)) * 8;

    const bf16* Ablk = A + (size_t)m0 * E_;
    const bf16* Bblk = W + (size_t)n0 * E_;
    f32x4 acc[4][4] = {};

    {
        bf16 *Ac = &As[0][0], *An = &As[1][0], *Af = &As[2][0];
        bf16 *Bc = &Bs[0][0], *Bn = &Bs[1][0], *Bf = &Bs[2][0];
        STG_A(Ac, 0, 0);  STG_A(Ac, 0, 1);  STG_A(Ac, 0, 2);  STG_A(Ac, 0, 3);
        STG_B(Bc, 0, 0);  STG_B(Bc, 0, 1);
        STG_A(An, 64, 0); STG_A(An, 64, 1); STG_A(An, 64, 2); STG_A(An, 64, 3);
        STG_B(Bn, 64, 0); STG_B(Bn, 64, 1);
        for (int kt = 0; kt < 16; ++kt) {
            if (kt < 15) asm volatile("s_waitcnt vmcnt(6)\n\ts_barrier" ::: "memory");
            else         asm volatile("s_waitcnt vmcnt(0)\n\ts_barrier" ::: "memory");
            const int kk2 = (kt + 2) * 64;
            const bool st = (kt < 14);
            bf16x8 af[2][2], bw[4][2];
            #pragma unroll
            for (int i2 = 0; i2 < 2; ++i2) {
                int ra = wro + i2 * 16 + l15;
                af[i2][0] = LDF(Ac, ra, 0); af[i2][1] = LDF(Ac, ra, 1);
            }
            #pragma unroll
            for (int j = 0; j < 4; ++j) {
                int rb = wco + j * 16 + l15;
                bw[j][0] = LDF(Bc, rb, 0); bw[j][1] = LDF(Bc, rb, 1);
            }
            if (st) { STG_A(Af, kk2, 0); STG_A(Af, kk2, 1); STG_B(Bf, kk2, 0); }
            __builtin_amdgcn_s_setprio(1);
            #pragma unroll
            for (int i2 = 0; i2 < 2; ++i2)
                #pragma unroll
                for (int j = 0; j < 4; ++j) {
                    acc[i2][j] = mfma16(af[i2][0], bw[j][0], acc[i2][j]);
                    acc[i2][j] = mfma16(af[i2][1], bw[j][1], acc[i2][j]);
                }
            __builtin_amdgcn_s_setprio(0);
            asm volatile("s_barrier" ::: "memory");
            #pragma unroll
            for (int i2 = 0; i2 < 2; ++i2) {
                int ra = wro + (2 + i2) * 16 + l15;
                af[i2][0] = LDF(Ac, ra, 0); af[i2][1] = LDF(Ac, ra, 1);
            }
            if (st) { STG_A(Af, kk2, 2); STG_A(Af, kk2, 3); STG_B(Bf, kk2, 1); }
            __builtin_amdgcn_s_setprio(1);
            #pragma unroll
            for (int i2 = 0; i2 < 2; ++i2)
                #pragma unroll
                for (int j = 0; j < 4; ++j) {
                    acc[2 + i2][j] = mfma16(af[i2][0], bw[j][0], acc[2 + i2][j]);
                    acc[2 + i2][j] = mfma16(af[i2][1], bw[j][1], acc[2 + i2][j]);
                }
            __builtin_amdgcn_s_setprio(0);
            bf16* tp;
            tp = Ac; Ac = An; An = Af; Af = tp;
            tp = Bc; Bc = Bn; Bn = Bf; Bf = tp;
        }
    }

    #pragma unroll
    for (int i = 0; i < 4; ++i)
        #pragma unroll
        for (int j = 0; j < 4; ++j)
            #pragma unroll
            for (int r = 0; r < 4; ++r) {
                int mg = m0 + wro + i * 16 + quad * 4 + r;
                int ng = n0 + wco + j * 16 + l15;
                out[(size_t)mg * E_ + ng] = acc[i][j][r] + bias[ng];
            }
}

// ---------------------------------------------------------------- launch
extern "C" void kernel_launch(void* const* d_in, const int* in_sizes, int n_in,
                              void* d_out, int out_size, void* d_ws, size_t ws_size,
                              hipStream_t stream) {
    const float* x     = (const float*)d_in[0];   // [B,S,E]
    const float* w_in  = (const float*)d_in[1];   // [3E,E]
    const float* b_in  = (const float*)d_in[2];   // [3E]
    const float* w_out = (const float*)d_in[3];   // [E,E]
    const float* b_out = (const float*)d_in[4];   // [E]
    float* out = (float*)d_out;

    char* ws = (char*)d_ws;
    bf16* Xbf  = (bf16*)ws; ws += (size_t)M_ * E_ * 2;
    bf16* Wqkv = (bf16*)ws; ws += (size_t)N3_ * E_ * 2;
    bf16* Wo   = (bf16*)ws; ws += (size_t)E_ * E_ * 2;
    bf16* QKV  = (bf16*)ws; ws += (size_t)2 * B_ * H_ * S_ * D_ * 2;  // Q,K only
    bf16* Vt   = (bf16*)ws; ws += (size_t)B_ * H_ * S_ * D_ * 2;
    bf16* Obf  = Xbf;   // Xbf dead after gemm_qkv

    const int nCvt = (M_ * E_ + N3_ * E_ + E_ * E_) / 4;
    cvt_all<<<(nCvt + 255) / 256, 256, 0, stream>>>(x, w_in, w_out, Xbf, Wqkv, Wo);

    gemm_qkv<<<dim3(N3_ / 128, M_ / 128), 256, 0, stream>>>(Xbf, Wqkv, b_in, QKV, Vt);

    bf16* Qp = QKV;
    bf16* Kp = QKV + (size_t)B_ * H_ * S_ * D_;

    attn8<<<dim3(8 * B_ * H_), 512, 0, stream>>>(Qp, Kp, Vt, Obf);

    gemm_out<<<dim3(E_ / 128, M_ / 256), 512, 0, stream>>>(Obf, Wo, b_out, out);
}

// Round 5
// 233.111 us; speedup vs baseline: 1.0073x; 1.0073x over previous
//
#include <hip/hip_runtime.h>
#include <hip/hip_bf16.h>

// Problem constants (SelfAttention: B=4, S=2048, E=1024, H=16, D=64)
#define B_  4
#define S_  2048
#define E_  1024
#define H_  16
#define D_  64
#define M_  (B_*S_)     // 8192
#define N3_ (3*E_)      // 3072

typedef __bf16 bf16;
typedef bf16  bf16x4 __attribute__((ext_vector_type(4)));
typedef bf16  bf16x8 __attribute__((ext_vector_type(8)));
typedef float f32x4  __attribute__((ext_vector_type(4)));

#define SC2 0.18033688011112043f   // (1/sqrt(64)) * log2(e), folded into Q

__device__ __forceinline__ f32x4 mfma16(bf16x8 a, bf16x8 b, f32x4 c) {
    return __builtin_amdgcn_mfma_f32_16x16x32_bf16(a, b, c, 0, 0, 0);
}

typedef const __attribute__((address_space(1))) void* gas_t;
typedef __attribute__((address_space(3))) void* las_t;
__device__ __forceinline__ void gl_lds16(const void* g, void* l) {
    __builtin_amdgcn_global_load_lds((gas_t)g, (las_t)l, 16, 0, 0);
}

// s_waitcnt imm = (vm_hi<<14)|(lgkm<<8)|(exp<<4)|vm_lo ; lgkm=15,exp=7 = no-wait
#define WAITCNT_VM2() __builtin_amdgcn_s_waitcnt(0x0F72)   // vmcnt(2) only
#define WAITCNT_VM0() __builtin_amdgcn_s_waitcnt(0x0F70)   // vmcnt(0) only

// ---------------------------------------------------------------- fp32->bf16 (all 3 tensors, one launch)
__global__ __launch_bounds__(256) void cvt_all(const float* __restrict__ x,
                                               const float* __restrict__ w_in,
                                               const float* __restrict__ w_out,
                                               bf16* __restrict__ Xbf,
                                               bf16* __restrict__ Wqkv,
                                               bf16* __restrict__ Wo) {
    const int n1 = M_ * E_ / 4, n2 = N3_ * E_ / 4, n3 = E_ * E_ / 4;
    int i = blockIdx.x * blockDim.x + threadIdx.x;
    const float* src; bf16* dst; int j;
    if (i < n1)           { src = x;     dst = Xbf;  j = i; }
    else if (i < n1 + n2) { src = w_in;  dst = Wqkv; j = i - n1; }
    else if (i < n1 + n2 + n3) { src = w_out; dst = Wo; j = i - n1 - n2; }
    else return;
    float4 v = *(const float4*)(src + (size_t)j * 4);
    bf16x4 o;
    o[0] = (bf16)v.x; o[1] = (bf16)v.y; o[2] = (bf16)v.z; o[3] = (bf16)v.w;
    *(bf16x4*)(dst + (size_t)j * 4) = o;
}

// ---------------------------------------------------------------- QKV GEMM (R0 structure + XCD 2D chunking)
// 128x128 tile, BK=64 (XOR-swizzled LDS), 4 waves 2x2, each 64x64 (4x4 frags).
// Q/K blocks (n0<2048): C = X·W^T, scatter to Q/K [B,H,S,D]; Q pre-scaled SC2.
// V blocks (n0>=2048): operands swapped (C = W·X^T) so C rows = d, cols = s;
// epilogue writes Vt[bh][d][s] directly — the V transpose is free.
// R5: XCD-aware 2D remap. Default (xcd=bx%8) gives each XCD 3 n-tiles of W
// (0.75MB) but ALL 64 A-panels (16MB) through its 4MB L2 -> X over-fetch
// (FETCH 76.9MB vs 22MB ideal). Remap: each XCD owns 16 m-tiles x 12 n-tiles
// (n-fast): per-XCD footprint ~W 3MB + few A-panels; X shared by 2 XCDs,
// W by 4 -> predicted FETCH ~55-60MB. Bijective: L<->(xcd,slot)<->(mt,nt).
// History: R1 triple-buffer counted-vmcnt NEUTRAL; 256² 8-phase rejected
// (gain x 75% grid-round efficiency = wash).
__global__ __launch_bounds__(256) void gemm_qkv(const bf16* __restrict__ X,
                                                const bf16* __restrict__ W,
                                                const float* __restrict__ bias,
                                                bf16* __restrict__ QKV,
                                                bf16* __restrict__ Vt) {
    __shared__ __align__(16) bf16 As[128 * 64];
    __shared__ __align__(16) bf16 Bs[128 * 64];
    const int t = threadIdx.x;
    const int wav = t >> 6, lane = t & 63, quad = lane >> 4, l15 = lane & 15;

    // XCD-aware 2D chunk remap (8 XCDs = 4 m-groups x 2 n-groups)
    const int L    = blockIdx.y * 24 + blockIdx.x;   // 0..1535
    const int xcd  = L & 7;
    const int slot = L >> 3;                         // 0..191
    const int nl   = slot % 12, ml = slot / 12;      // n-fast within chunk
    const int mt   = (xcd >> 1) * 16 + ml;           // 0..63
    const int nt   = (xcd & 1) * 12 + nl;            // 0..23
    const int m0 = mt * 128, n0 = nt * 128;

    const int wr = (wav >> 1) * 64, wc = (wav & 1) * 64;
    const int srow = t >> 3;
    const int swz  = ((t & 7) ^ (srow & 7)) * 8;
    const bool isV = (n0 >= 2 * E_);

    const bf16* Ablk = X + (size_t)m0 * E_;
    const bf16* Bblk = W + (size_t)n0 * E_;
    f32x4 acc[4][4] = {};

    for (int kk = 0; kk < E_; kk += 64) {
        __syncthreads();
        #pragma unroll
        for (int ps = 0; ps < 4; ++ps) {
            gl_lds16(Ablk + (size_t)(srow + ps * 32) * E_ + kk + swz, As + (size_t)(t + ps * 256) * 8);
            gl_lds16(Bblk + (size_t)(srow + ps * 32) * E_ + kk + swz, Bs + (size_t)(t + ps * 256) * 8);
        }
        __syncthreads();
        #pragma unroll
        for (int ks = 0; ks < 2; ++ks) {
            bf16x8 af[4], bw[4];
            #pragma unroll
            for (int i = 0; i < 4; ++i) {
                const int ra = wr + i * 16 + l15;
                const int rb = wc + i * 16 + l15;
                const int cx = ((ks * 4 + quad) ^ (l15 & 7)) * 8;
                af[i] = *(const bf16x8*)&As[ra * 64 + cx];
                bw[i] = *(const bf16x8*)&Bs[rb * 64 + cx];
            }
            if (!isV) {
                #pragma unroll
                for (int i = 0; i < 4; ++i)
                    #pragma unroll
                    for (int j = 0; j < 4; ++j)
                        acc[i][j] = mfma16(af[i], bw[j], acc[i][j]);
            } else {
                #pragma unroll
                for (int i = 0; i < 4; ++i)
                    #pragma unroll
                    for (int j = 0; j < 4; ++j)
                        acc[i][j] = mfma16(bw[i], af[j], acc[i][j]);
            }
        }
    }
    if (!isV) {
        // C row = m (quad*4+r), col = n (l15)
        #pragma unroll
        for (int i = 0; i < 4; ++i)
            #pragma unroll
            for (int j = 0; j < 4; ++j)
                #pragma unroll
                for (int r = 0; r < 4; ++r) {
                    int mg = m0 + wr + i * 16 + quad * 4 + r;
                    int ng = n0 + wc + j * 16 + l15;
                    float v = acc[i][j][r] + bias[ng];
                    int which = ng >> 10, rem = ng & 1023;
                    if (which == 0) v *= SC2;
                    int h = rem >> 6, d = rem & 63;
                    int b = mg >> 11, s = mg & 2047;
                    QKV[(size_t)which * (B_ * H_ * S_ * D_) +
                        (((size_t)(b * H_ + h) * S_ + s) * D_ + d)] = (bf16)v;
                }
    } else {
        // C row = n (d dim), col = m (s dim): write Vt[bh][d][s]
        #pragma unroll
        for (int i = 0; i < 4; ++i)
            #pragma unroll
            for (int j = 0; j < 4; ++j)
                #pragma unroll
                for (int r = 0; r < 4; ++r) {
                    int ng = n0 + wc + i * 16 + quad * 4 + r;
                    int mg = m0 + wr + j * 16 + l15;
                    float v = acc[i][j][r] + bias[ng];
                    int rem = ng & 1023;
                    int h = rem >> 6, d = rem & 63;
                    int b = mg >> 11, s = mg & 2047;
                    Vt[(((size_t)(b * H_ + h) * D_ + d) * S_) + s] = (bf16)v;
                }
    }
}

// ---------------------------------------------------------------- attention (R0 verbatim — best measured, ~61.6us)
// R2 (32 q/wave): -10us. R3 (KT=128): -3.8us. R4 (tribuf+setprio+skip): -3us.
// This structure is the local optimum: 16 q/wave, 8-wave blocks over 128 q
// rows, KT=64 double-buffer, 2 blocks/CU = 4 waves/SIMD. DO NOT RESTRUCTURE.
__global__ __launch_bounds__(512, 4) void attn8(const bf16* __restrict__ Q,
                                                const bf16* __restrict__ K,
                                                const bf16* __restrict__ Vt,
                                                bf16* __restrict__ O) {
    __shared__ __align__(16) bf16 Ks[2][64 * 64];      // [buf][key][d]   (XOR-swizzled chunks)
    __shared__ __align__(16) bf16 Vs[2][64 * 64];      // [buf][d][key]   (XOR-swizzled chunks)
    __shared__ __align__(16) bf16 Ps[8][16 * 64];      // per-wave P, XOR-swizzled chunks

    const int t = threadIdx.x;
    const int wav = t >> 6, lane = t & 63, quad = lane >> 4, l15 = lane & 15;
    const int p  = blockIdx.x >> 6;      // pair index 0..7
    const int bh = blockIdx.x & 63;

    const bf16* Qb = Q  + (size_t)bh * S_ * D_;
    const bf16* Kb = K  + (size_t)bh * S_ * D_;
    const bf16* Vb = Vt + (size_t)bh * (size_t)D_ * S_;   // [d][s]

    const int srow = t >> 3;                      // staging row 0..63
    const int swz  = ((t & 7) ^ (srow & 7)) * 8;  // swizzled global chunk offset
    bf16* Pw = &Ps[wav][0];
    const int pswz = l15 & 7;                     // P chunk swizzle key

    const int b = bh >> 4, h = bh & 15;

    #pragma unroll 1
    for (int phase = 0; phase < 2; ++phase) {
        const int qb  = phase ? (15 - p) : p;     // q-tile of 128
        const int q0w = qb * 128 + wav * 16;
        const int qg  = q0w + l15;
        const int niter = 2 * qb + 2;

        __builtin_amdgcn_s_barrier();   // prior phase's buf reads complete
        // preload tile 0 -> buf 0 (2 DMAs/thread: 1 K, 1 V)
        gl_lds16(Kb + (size_t)srow * D_ + swz, &Ks[0][(size_t)t * 8]);
        gl_lds16(Vb + (size_t)srow * S_ + swz, &Vs[0][(size_t)t * 8]);

        bf16x8 qf0 = *(const bf16x8*)&Qb[(size_t)(q0w + l15) * D_ + quad * 8];
        bf16x8 qf1 = *(const bf16x8*)&Qb[(size_t)(q0w + l15) * D_ + 32 + quad * 8];

        f32x4 oacc[4] = {};
        f32x4 psum = {0.f, 0.f, 0.f, 0.f};   // per-lane partial row sums (by r)

        #pragma unroll 1
        for (int it = 0; it < niter; ++it) {
            const int key0 = it * 64;
            const int cur = it & 1;
            const bf16* Kc = &Ks[cur][0];
            const bf16* Vc = &Vs[cur][0];

            __builtin_amdgcn_s_barrier();          // all waves done reading buf[1-cur]
            if (it + 1 < niter) {                  // issue tile it+1 -> buf[1-cur]
                const int kn = key0 + 64;
                gl_lds16(Kb + (size_t)(kn + srow) * D_ + swz, &Ks[1 - cur][(size_t)t * 8]);
                gl_lds16(Vb + (size_t)srow * S_ + kn + swz,   &Vs[1 - cur][(size_t)t * 8]);
                WAITCNT_VM2();                     // only tile it's 2 DMAs must be done
            } else {
                WAITCNT_VM0();
            }
            __builtin_amdgcn_s_barrier();          // tile it visible to all waves

            // --- QK^T -> S^T tiles (rows=key, cols=q); Q pre-scaled
            f32x4 sacc[4];
            #pragma unroll
            for (int mt = 0; mt < 4; ++mt) {
                const int krow = mt * 16 + l15;
                const int sw = krow & 7;
                bf16x8 kf0 = *(const bf16x8*)&Kc[krow * 64 + ((quad ^ sw) * 8)];
                bf16x8 kf1 = *(const bf16x8*)&Kc[krow * 64 + (((4 + quad) ^ sw) * 8)];
                f32x4 a = {};
                a = mfma16(kf0, qf0, a);
                a = mfma16(kf1, qf1, a);
                sacc[mt] = a;
            }

            // --- causal mask (diagonal tiles only)
            #pragma unroll
            for (int mt = 0; mt < 4; ++mt) {
                if (key0 + mt * 16 + 15 > q0w) {   // wave-uniform branch
                    #pragma unroll
                    for (int r = 0; r < 4; ++r) {
                        int key = key0 + mt * 16 + quad * 4 + r;
                        sacc[mt][r] = (key > qg) ? -3e38f : sacc[mt][r];
                    }
                }
            }

            // --- P = exp2(S) (no max-sub; lane-local), accumulate row sums,
            //     pack to bf16, write to per-wave swizzled P buffer
            #pragma unroll
            for (int mt = 0; mt < 4; ++mt) {
                bf16x4 pk;
                #pragma unroll
                for (int r = 0; r < 4; ++r) {
                    float pv = __builtin_amdgcn_exp2f(sacc[mt][r]);
                    psum[r] += pv;
                    pk[r] = (bf16)pv;
                }
                const int pc = ((mt * 2 + (quad >> 1)) ^ pswz) * 8 + (quad & 1) * 4;
                *(bf16x4*)&Pw[l15 * 64 + pc] = pk;
            }

            // --- PV: a = P rows (swizzled b128), b = Vt rows (swizzled b128)
            bf16x8 pf0 = *(const bf16x8*)&Pw[l15 * 64 + ((quad ^ pswz) * 8)];
            bf16x8 pf1 = *(const bf16x8*)&Pw[l15 * 64 + (((4 + quad) ^ pswz) * 8)];
            #pragma unroll
            for (int nt = 0; nt < 4; ++nt) {
                const int vrow = nt * 16 + l15;
                const int sw = vrow & 7;
                bf16x8 vf0 = *(const bf16x8*)&Vc[vrow * 64 + ((quad ^ sw) * 8)];
                bf16x8 vf1 = *(const bf16x8*)&Vc[vrow * 64 + (((4 + quad) ^ sw) * 8)];
                oacc[nt] = mfma16(pf0, vf0, oacc[nt]);
                oacc[nt] = mfma16(pf1, vf1, oacc[nt]);
            }
        }

        // --- deferred softmax denominator: one cross-quad reduction per phase
        float rsum = psum[0] + psum[1] + psum[2] + psum[3];
        rsum += __shfl_xor(rsum, 16);
        rsum += __shfl_xor(rsum, 32);
        const float linv = 1.0f / rsum;

        // --- phase epilogue: O[b, q, h*64 + d] = oacc / l
        #pragma unroll
        for (int rr = 0; rr < 4; ++rr) {
            float li = __shfl(linv, quad * 4 + rr);
            const int q = q0w + quad * 4 + rr;
            #pragma unroll
            for (int nt = 0; nt < 4; ++nt)
                O[((size_t)b * S_ + q) * E_ + h * D_ + nt * 16 + l15] =
                    (bf16)(oacc[nt][rr] * li);
        }
    }
}

// ---------------------------------------------------------------- out GEMM (R1 pipelined version, proven -4.7us vs R0)
// 256x128 tile, BK=64, 8 waves (4M x 2N). Triple-buffered LDS, counted
// vmcnt(6) head-of-window, setprio around MFMA clusters. 256 blocks = 1
// exact round of 256 CUs. Default mapping already XCD-column-partitioned
// (bx is exactly 8-wide -> xcd = bx = n-column) — no remap needed.
#define STG_A(dst, kk, ps) gl_lds16(Ablk + (size_t)(srow + (ps)*64)*E_ + (kk) + swz, (dst) + (size_t)(t + (ps)*512)*8)
#define STG_B(dst, kk, ps) gl_lds16(Bblk + (size_t)(srow + (ps)*64)*E_ + (kk) + swz, (dst) + (size_t)(t + (ps)*512)*8)
#define LDF(base, row, ks) (*(const bf16x8*)&(base)[(row)*64 + ((((ks)*4 + quad) ^ ((row)&7))*8)])

__global__ __launch_bounds__(512, 2) void gemm_out(const bf16* __restrict__ A,
                                                   const bf16* __restrict__ W,
                                                   const float* __restrict__ bias,
                                                   float* __restrict__ out) {
    __shared__ __align__(16) bf16 As[3][256 * 64];
    __shared__ __align__(16) bf16 Bs[3][128 * 64];
    const int t = threadIdx.x;
    const int wav = t >> 6, lane = t & 63, quad = lane >> 4, l15 = lane & 15;
    const int m0 = blockIdx.y * 256, n0 = blockIdx.x * 128;
    const int wro = (wav >> 1) * 64, wco = (wav & 1) * 64;
    const int srow = t >> 3;
    const int swz  = ((t & 7) ^ (srow & 7)) * 8;

    const bf16* Ablk = A + (size_t)m0 * E_;
    const bf16* Bblk = W + (size_t)n0 * E_;
    f32x4 acc[4][4] = {};

    {
        bf16 *Ac = &As[0][0], *An = &As[1][0], *Af = &As[2][0];
        bf16 *Bc = &Bs[0][0], *Bn = &Bs[1][0], *Bf = &Bs[2][0];
        STG_A(Ac, 0, 0);  STG_A(Ac, 0, 1);  STG_A(Ac, 0, 2);  STG_A(Ac, 0, 3);
        STG_B(Bc, 0, 0);  STG_B(Bc, 0, 1);
        STG_A(An, 64, 0); STG_A(An, 64, 1); STG_A(An, 64, 2); STG_A(An, 64, 3);
        STG_B(Bn, 64, 0); STG_B(Bn, 64, 1);
        for (int kt = 0; kt < 16; ++kt) {
            if (kt < 15) asm volatile("s_waitcnt vmcnt(6)\n\ts_barrier" ::: "memory");
            else         asm volatile("s_waitcnt vmcnt(0)\n\ts_barrier" ::: "memory");
            const int kk2 = (kt + 2) * 64;
            const bool st = (kt < 14);
            bf16x8 af[2][2], bw[4][2];
            #pragma unroll
            for (int i2 = 0; i2 < 2; ++i2) {
                int ra = wro + i2 * 16 + l15;
                af[i2][0] = LDF(Ac, ra, 0); af[i2][1] = LDF(Ac, ra, 1);
            }
            #pragma unroll
            for (int j = 0; j < 4; ++j) {
                int rb = wco + j * 16 + l15;
                bw[j][0] = LDF(Bc, rb, 0); bw[j][1] = LDF(Bc, rb, 1);
            }
            if (st) { STG_A(Af, kk2, 0); STG_A(Af, kk2, 1); STG_B(Bf, kk2, 0); }
            __builtin_amdgcn_s_setprio(1);
            #pragma unroll
            for (int i2 = 0; i2 < 2; ++i2)
                #pragma unroll
                for (int j = 0; j < 4; ++j) {
                    acc[i2][j] = mfma16(af[i2][0], bw[j][0], acc[i2][j]);
                    acc[i2][j] = mfma16(af[i2][1], bw[j][1], acc[i2][j]);
                }
            __builtin_amdgcn_s_setprio(0);
            asm volatile("s_barrier" ::: "memory");
            #pragma unroll
            for (int i2 = 0; i2 < 2; ++i2) {
                int ra = wro + (2 + i2) * 16 + l15;
                af[i2][0] = LDF(Ac, ra, 0); af[i2][1] = LDF(Ac, ra, 1);
            }
            if (st) { STG_A(Af, kk2, 2); STG_A(Af, kk2, 3); STG_B(Bf, kk2, 1); }
            __builtin_amdgcn_s_setprio(1);
            #pragma unroll
            for (int i2 = 0; i2 < 2; ++i2)
                #pragma unroll
                for (int j = 0; j < 4; ++j) {
                    acc[2 + i2][j] = mfma16(af[i2][0], bw[j][0], acc[2 + i2][j]);
                    acc[2 + i2][j] = mfma16(af[i2][1], bw[j][1], acc[2 + i2][j]);
                }
            __builtin_amdgcn_s_setprio(0);
            bf16* tp;
            tp = Ac; Ac = An; An = Af; Af = tp;
            tp = Bc; Bc = Bn; Bn = Bf; Bf = tp;
        }
    }

    #pragma unroll
    for (int i = 0; i < 4; ++i)
        #pragma unroll
        for (int j = 0; j < 4; ++j)
            #pragma unroll
            for (int r = 0; r < 4; ++r) {
                int mg = m0 + wro + i * 16 + quad * 4 + r;
                int ng = n0 + wco + j * 16 + l15;
                out[(size_t)mg * E_ + ng] = acc[i][j][r] + bias[ng];
            }
}

// ---------------------------------------------------------------- launch
extern "C" void kernel_launch(void* const* d_in, const int* in_sizes, int n_in,
                              void* d_out, int out_size, void* d_ws, size_t ws_size,
                              hipStream_t stream) {
    const float* x     = (const float*)d_in[0];   // [B,S,E]
    const float* w_in  = (const float*)d_in[1];   // [3E,E]
    const float* b_in  = (const float*)d_in[2];   // [3E]
    const float* w_out = (const float*)d_in[3];   // [E,E]
    const float* b_out = (const float*)d_in[4];   // [E]
    float* out = (float*)d_out;

    char* ws = (char*)d_ws;
    bf16* Xbf  = (bf16*)ws; ws += (size_t)M_ * E_ * 2;
    bf16* Wqkv = (bf16*)ws; ws += (size_t)N3_ * E_ * 2;
    bf16* Wo   = (bf16*)ws; ws += (size_t)E_ * E_ * 2;
    bf16* QKV  = (bf16*)ws; ws += (size_t)2 * B_ * H_ * S_ * D_ * 2;  // Q,K only
    bf16* Vt   = (bf16*)ws; ws += (size_t)B_ * H_ * S_ * D_ * 2;
    bf16* Obf  = Xbf;   // Xbf dead after gemm_qkv

    const int nCvt = (M_ * E_ + N3_ * E_ + E_ * E_) / 4;
    cvt_all<<<(nCvt + 255) / 256, 256, 0, stream>>>(x, w_in, w_out, Xbf, Wqkv, Wo);

    gemm_qkv<<<dim3(N3_ / 128, M_ / 128), 256, 0, stream>>>(Xbf, Wqkv, b_in, QKV, Vt);

    bf16* Qp = QKV;
    bf16* Kp = QKV + (size_t)B_ * H_ * S_ * D_;

    attn8<<<dim3(8 * B_ * H_), 512, 0, stream>>>(Qp, Kp, Vt, Obf);

    gemm_out<<<dim3(E_ / 128, M_ / 256), 512, 0, stream>>>(Obf, Wo, b_out, out);
}

// Round 9
// 228.749 us; speedup vs baseline: 1.0266x; 1.0191x over previous
//
#include <hip/hip_runtime.h>
#include <hip/hip_bf16.h>

// Problem constants (SelfAttention: B=4, S=2048, E=1024, H=16, D=64)
#define B_  4
#define S_  2048
#define E_  1024
#define H_  16
#define D_  64
#define M_  (B_*S_)     // 8192
#define N3_ (3*E_)      // 3072

typedef __bf16 bf16;
typedef bf16  bf16x4 __attribute__((ext_vector_type(4)));
typedef bf16  bf16x8 __attribute__((ext_vector_type(8)));
typedef float f32x4  __attribute__((ext_vector_type(4)));

#define SC2 0.18033688011112043f   // (1/sqrt(64)) * log2(e), folded into Q

__device__ __forceinline__ f32x4 mfma16(bf16x8 a, bf16x8 b, f32x4 c) {
    return __builtin_amdgcn_mfma_f32_16x16x32_bf16(a, b, c, 0, 0, 0);
}

typedef const __attribute__((address_space(1))) void* gas_t;
typedef __attribute__((address_space(3))) void* las_t;
__device__ __forceinline__ void gl_lds16(const void* g, void* l) {
    __builtin_amdgcn_global_load_lds((gas_t)g, (las_t)l, 16, 0, 0);
}

// s_waitcnt imm = (vm_hi<<14)|(lgkm<<8)|(exp<<4)|vm_lo ; lgkm=15,exp=7 = no-wait
#define WAITCNT_VM2() __builtin_amdgcn_s_waitcnt(0x0F72)   // vmcnt(2) only
#define WAITCNT_VM0() __builtin_amdgcn_s_waitcnt(0x0F70)   // vmcnt(0) only

// ---------------------------------------------------------------- fp32->bf16 (all 3 tensors, one launch)
// R6: grid-stride with capped grid (G11) — was 12,300 one-shot blocks.
__global__ __launch_bounds__(256) void cvt_all(const float* __restrict__ x,
                                               const float* __restrict__ w_in,
                                               const float* __restrict__ w_out,
                                               bf16* __restrict__ Xbf,
                                               bf16* __restrict__ Wqkv,
                                               bf16* __restrict__ Wo) {
    const int n1 = M_ * E_ / 4, n2 = N3_ * E_ / 4, n3 = E_ * E_ / 4;
    const int n  = n1 + n2 + n3;
    for (int i = blockIdx.x * blockDim.x + threadIdx.x; i < n;
         i += gridDim.x * blockDim.x) {
        const float* src; bf16* dst; int j;
        if (i < n1)           { src = x;     dst = Xbf;  j = i; }
        else if (i < n1 + n2) { src = w_in;  dst = Wqkv; j = i - n1; }
        else                  { src = w_out; dst = Wo;   j = i - n1 - n2; }
        float4 v = *(const float4*)(src + (size_t)j * 4);
        bf16x4 o;
        o[0] = (bf16)v.x; o[1] = (bf16)v.y; o[2] = (bf16)v.z; o[3] = (bf16)v.w;
        *(bf16x4*)(dst + (size_t)j * 4) = o;
    }
}

// ---------------------------------------------------------------- QKV GEMM (R5 version — structural ceiling)
// 128x128 tile, BK=64 (XOR-swizzled LDS), 4 waves 2x2, each 64x64 (4x4 frags).
// XCD-aware 2D remap (R5): FETCH 76.9->55.4MB, dur neutral -> proven
// issue/structure-bound, not L2-miss-bound. R1 pipeline depth: also neutral.
// 8-phase 256² rejected: 1.10x (m248, K=1024) x 0.75 round-eff < 1. CEILING.
__global__ __launch_bounds__(256) void gemm_qkv(const bf16* __restrict__ X,
                                                const bf16* __restrict__ W,
                                                const float* __restrict__ bias,
                                                bf16* __restrict__ QKV,
                                                bf16* __restrict__ Vt) {
    __shared__ __align__(16) bf16 As[128 * 64];
    __shared__ __align__(16) bf16 Bs[128 * 64];
    const int t = threadIdx.x;
    const int wav = t >> 6, lane = t & 63, quad = lane >> 4, l15 = lane & 15;

    // XCD-aware 2D chunk remap (8 XCDs = 4 m-groups x 2 n-groups)
    const int L    = blockIdx.y * 24 + blockIdx.x;   // 0..1535
    const int xcd  = L & 7;
    const int slot = L >> 3;                         // 0..191
    const int nl   = slot % 12, ml = slot / 12;      // n-fast within chunk
    const int mt   = (xcd >> 1) * 16 + ml;           // 0..63
    const int nt   = (xcd & 1) * 12 + nl;            // 0..23
    const int m0 = mt * 128, n0 = nt * 128;

    const int wr = (wav >> 1) * 64, wc = (wav & 1) * 64;
    const int srow = t >> 3;
    const int swz  = ((t & 7) ^ (srow & 7)) * 8;
    const bool isV = (n0 >= 2 * E_);

    const bf16* Ablk = X + (size_t)m0 * E_;
    const bf16* Bblk = W + (size_t)n0 * E_;
    f32x4 acc[4][4] = {};

    for (int kk = 0; kk < E_; kk += 64) {
        __syncthreads();
        #pragma unroll
        for (int ps = 0; ps < 4; ++ps) {
            gl_lds16(Ablk + (size_t)(srow + ps * 32) * E_ + kk + swz, As + (size_t)(t + ps * 256) * 8);
            gl_lds16(Bblk + (size_t)(srow + ps * 32) * E_ + kk + swz, Bs + (size_t)(t + ps * 256) * 8);
        }
        __syncthreads();
        #pragma unroll
        for (int ks = 0; ks < 2; ++ks) {
            bf16x8 af[4], bw[4];
            #pragma unroll
            for (int i = 0; i < 4; ++i) {
                const int ra = wr + i * 16 + l15;
                const int rb = wc + i * 16 + l15;
                const int cx = ((ks * 4 + quad) ^ (l15 & 7)) * 8;
                af[i] = *(const bf16x8*)&As[ra * 64 + cx];
                bw[i] = *(const bf16x8*)&Bs[rb * 64 + cx];
            }
            if (!isV) {
                #pragma unroll
                for (int i = 0; i < 4; ++i)
                    #pragma unroll
                    for (int j = 0; j < 4; ++j)
                        acc[i][j] = mfma16(af[i], bw[j], acc[i][j]);
            } else {
                #pragma unroll
                for (int i = 0; i < 4; ++i)
                    #pragma unroll
                    for (int j = 0; j < 4; ++j)
                        acc[i][j] = mfma16(bw[i], af[j], acc[i][j]);
            }
        }
    }
    if (!isV) {
        // C row = m (quad*4+r), col = n (l15)
        #pragma unroll
        for (int i = 0; i < 4; ++i)
            #pragma unroll
            for (int j = 0; j < 4; ++j)
                #pragma unroll
                for (int r = 0; r < 4; ++r) {
                    int mg = m0 + wr + i * 16 + quad * 4 + r;
                    int ng = n0 + wc + j * 16 + l15;
                    float v = acc[i][j][r] + bias[ng];
                    int which = ng >> 10, rem = ng & 1023;
                    if (which == 0) v *= SC2;
                    int h = rem >> 6, d = rem & 63;
                    int b = mg >> 11, s = mg & 2047;
                    QKV[(size_t)which * (B_ * H_ * S_ * D_) +
                        (((size_t)(b * H_ + h) * S_ + s) * D_ + d)] = (bf16)v;
                }
    } else {
        // C row = n (d dim), col = m (s dim): write Vt[bh][d][s]
        #pragma unroll
        for (int i = 0; i < 4; ++i)
            #pragma unroll
            for (int j = 0; j < 4; ++j)
                #pragma unroll
                for (int r = 0; r < 4; ++r) {
                    int ng = n0 + wc + i * 16 + quad * 4 + r;
                    int mg = m0 + wr + j * 16 + l15;
                    float v = acc[i][j][r] + bias[ng];
                    int rem = ng & 1023;
                    int h = rem >> 6, d = rem & 63;
                    int b = mg >> 11, s = mg & 2047;
                    Vt[(((size_t)(b * H_ + h) * D_ + d) * S_) + s] = (bf16)v;
                }
    }
}

// ---------------------------------------------------------------- attention
// R6: R0 structure (local optimum — 3 restructures lost) + MFMA row-sum.
// Counters (R2 profile): VALUBusy 38 > MfmaUtil 22 -> VALU-bound inner loop.
// Replace the 16 psum f32 adds/iter + 7 epilogue shuffles with 2 MFMAs/iter
// against a ones-B-fragment: A-row(l15=q) -> C-row(quad*4+r), so lacc[r] =
// rowsum(q=q0w+quad*4+r) lands exactly where the epilogue consumes it —
// no cross-lane ops. Denominator now sums bf16-rounded P (same P as the PV
// numerator); random rounding -> relative shift ~6e-5, far below output ulp.
// Rejected on paper (recorded): T12 in-reg P (needs 16 bpermutes here due to
// quad-crossed C->A-frag layout); 16x16x16-PV (+80 LDS-conflict cyc vs -52;
// Vs layout locked by global_load_lds linear dest, m104).
__global__ __launch_bounds__(512, 4) void attn8(const bf16* __restrict__ Q,
                                                const bf16* __restrict__ K,
                                                const bf16* __restrict__ Vt,
                                                bf16* __restrict__ O) {
    __shared__ __align__(16) bf16 Ks[2][64 * 64];      // [buf][key][d]   (XOR-swizzled chunks)
    __shared__ __align__(16) bf16 Vs[2][64 * 64];      // [buf][d][key]   (XOR-swizzled chunks)
    __shared__ __align__(16) bf16 Ps[8][16 * 64];      // per-wave P, XOR-swizzled chunks

    const int t = threadIdx.x;
    const int wav = t >> 6, lane = t & 63, quad = lane >> 4, l15 = lane & 15;
    const int p  = blockIdx.x >> 6;      // pair index 0..7
    const int bh = blockIdx.x & 63;

    const bf16* Qb = Q  + (size_t)bh * S_ * D_;
    const bf16* Kb = K  + (size_t)bh * S_ * D_;
    const bf16* Vb = Vt + (size_t)bh * (size_t)D_ * S_;   // [d][s]

    const int srow = t >> 3;                      // staging row 0..63
    const int swz  = ((t & 7) ^ (srow & 7)) * 8;  // swizzled global chunk offset
    bf16* Pw = &Ps[wav][0];
    const int pswz = l15 & 7;                     // P chunk swizzle key

    const int b = bh >> 4, h = bh & 15;

    bf16x8 ones;
    #pragma unroll
    for (int j = 0; j < 8; ++j) ones[j] = (bf16)1.0f;

    #pragma unroll 1
    for (int phase = 0; phase < 2; ++phase) {
        const int qb  = phase ? (15 - p) : p;     // q-tile of 128
        const int q0w = qb * 128 + wav * 16;
        const int qg  = q0w + l15;
        const int niter = 2 * qb + 2;

        __builtin_amdgcn_s_barrier();   // prior phase's buf reads complete
        // preload tile 0 -> buf 0 (2 DMAs/thread: 1 K, 1 V)
        gl_lds16(Kb + (size_t)srow * D_ + swz, &Ks[0][(size_t)t * 8]);
        gl_lds16(Vb + (size_t)srow * S_ + swz, &Vs[0][(size_t)t * 8]);

        bf16x8 qf0 = *(const bf16x8*)&Qb[(size_t)(q0w + l15) * D_ + quad * 8];
        bf16x8 qf1 = *(const bf16x8*)&Qb[(size_t)(q0w + l15) * D_ + 32 + quad * 8];

        f32x4 oacc[4] = {};
        f32x4 lacc = {};   // MFMA row sums: lacc[r] = sum_k P[q0w+quad*4+r][k]

        #pragma unroll 1
        for (int it = 0; it < niter; ++it) {
            const int key0 = it * 64;
            const int cur = it & 1;
            const bf16* Kc = &Ks[cur][0];
            const bf16* Vc = &Vs[cur][0];

            __builtin_amdgcn_s_barrier();          // all waves done reading buf[1-cur]
            if (it + 1 < niter) {                  // issue tile it+1 -> buf[1-cur]
                const int kn = key0 + 64;
                gl_lds16(Kb + (size_t)(kn + srow) * D_ + swz, &Ks[1 - cur][(size_t)t * 8]);
                gl_lds16(Vb + (size_t)srow * S_ + kn + swz,   &Vs[1 - cur][(size_t)t * 8]);
                WAITCNT_VM2();                     // only tile it's 2 DMAs must be done
            } else {
                WAITCNT_VM0();
            }
            __builtin_amdgcn_s_barrier();          // tile it visible to all waves

            // --- QK^T -> S^T tiles (rows=key, cols=q); Q pre-scaled
            f32x4 sacc[4];
            #pragma unroll
            for (int mt = 0; mt < 4; ++mt) {
                const int krow = mt * 16 + l15;
                const int sw = krow & 7;
                bf16x8 kf0 = *(const bf16x8*)&Kc[krow * 64 + ((quad ^ sw) * 8)];
                bf16x8 kf1 = *(const bf16x8*)&Kc[krow * 64 + (((4 + quad) ^ sw) * 8)];
                f32x4 a = {};
                a = mfma16(kf0, qf0, a);
                a = mfma16(kf1, qf1, a);
                sacc[mt] = a;
            }

            // --- causal mask (diagonal tiles only)
            #pragma unroll
            for (int mt = 0; mt < 4; ++mt) {
                if (key0 + mt * 16 + 15 > q0w) {   // wave-uniform branch
                    #pragma unroll
                    for (int r = 0; r < 4; ++r) {
                        int key = key0 + mt * 16 + quad * 4 + r;
                        sacc[mt][r] = (key > qg) ? -3e38f : sacc[mt][r];
                    }
                }
            }

            // --- P = exp2(S) (no max-sub; lane-local), pack to bf16, write
            //     to per-wave swizzled P buffer (row sums now via MFMA below)
            #pragma unroll
            for (int mt = 0; mt < 4; ++mt) {
                bf16x4 pk;
                #pragma unroll
                for (int r = 0; r < 4; ++r)
                    pk[r] = (bf16)__builtin_amdgcn_exp2f(sacc[mt][r]);
                const int pc = ((mt * 2 + (quad >> 1)) ^ pswz) * 8 + (quad & 1) * 4;
                *(bf16x4*)&Pw[l15 * 64 + pc] = pk;
            }

            // --- PV + MFMA row-sum: a = P rows (swizzled b128)
            bf16x8 pf0 = *(const bf16x8*)&Pw[l15 * 64 + ((quad ^ pswz) * 8)];
            bf16x8 pf1 = *(const bf16x8*)&Pw[l15 * 64 + (((4 + quad) ^ pswz) * 8)];
            lacc = mfma16(pf0, ones, lacc);
            lacc = mfma16(pf1, ones, lacc);
            #pragma unroll
            for (int nt = 0; nt < 4; ++nt) {
                const int vrow = nt * 16 + l15;
                const int sw = vrow & 7;
                bf16x8 vf0 = *(const bf16x8*)&Vc[vrow * 64 + ((quad ^ sw) * 8)];
                bf16x8 vf1 = *(const bf16x8*)&Vc[vrow * 64 + (((4 + quad) ^ sw) * 8)];
                oacc[nt] = mfma16(pf0, vf0, oacc[nt]);
                oacc[nt] = mfma16(pf1, vf1, oacc[nt]);
            }
        }

        // --- epilogue: lacc[rr] IS the row sum for q = q0w + quad*4 + rr
        //     (A-row -> C-row mapping) — no cross-lane reduction needed.
        #pragma unroll
        for (int rr = 0; rr < 4; ++rr) {
            const float li = 1.0f / lacc[rr];
            const int q = q0w + quad * 4 + rr;
            #pragma unroll
            for (int nt = 0; nt < 4; ++nt)
                O[((size_t)b * S_ + q) * E_ + h * D_ + nt * 16 + l15] =
                    (bf16)(oacc[nt][rr] * li);
        }
    }
}

// ---------------------------------------------------------------- out GEMM (R1 pipelined version, proven -4.7us vs R0)
// 256x128 tile, BK=64, 8 waves (4M x 2N). Triple-buffered LDS, counted
// vmcnt(6) head-of-window, setprio around MFMA clusters. 256 blocks = 1
// exact round of 256 CUs. Default mapping already XCD-column-partitioned.
#define STG_A(dst, kk, ps) gl_lds16(Ablk + (size_t)(srow + (ps)*64)*E_ + (kk) + swz, (dst) + (size_t)(t + (ps)*512)*8)
#define STG_B(dst, kk, ps) gl_lds16(Bblk + (size_t)(srow + (ps)*64)*E_ + (kk) + swz, (dst) + (size_t)(t + (ps)*512)*8)
#define LDF(base, row, ks) (*(const bf16x8*)&(base)[(row)*64 + ((((ks)*4 + quad) ^ ((row)&7))*8)])

__global__ __launch_bounds__(512, 2) void gemm_out(const bf16* __restrict__ A,
                                                   const bf16* __restrict__ W,
                                                   const float* __restrict__ bias,
                                                   float* __restrict__ out) {
    __shared__ __align__(16) bf16 As[3][256 * 64];
    __shared__ __align__(16) bf16 Bs[3][128 * 64];
    const int t = threadIdx.x;
    const int wav = t >> 6, lane = t & 63, quad = lane >> 4, l15 = lane & 15;
    const int m0 = blockIdx.y * 256, n0 = blockIdx.x * 128;
    const int wro = (wav >> 1) * 64, wco = (wav & 1) * 64;
    const int srow = t >> 3;
    const int swz  = ((t & 7) ^ (srow & 7)) * 8;

    const bf16* Ablk = A + (size_t)m0 * E_;
    const bf16* Bblk = W + (size_t)n0 * E_;
    f32x4 acc[4][4] = {};

    {
        bf16 *Ac = &As[0][0], *An = &As[1][0], *Af = &As[2][0];
        bf16 *Bc = &Bs[0][0], *Bn = &Bs[1][0], *Bf = &Bs[2][0];
        STG_A(Ac, 0, 0);  STG_A(Ac, 0, 1);  STG_A(Ac, 0, 2);  STG_A(Ac, 0, 3);
        STG_B(Bc, 0, 0);  STG_B(Bc, 0, 1);
        STG_A(An, 64, 0); STG_A(An, 64, 1); STG_A(An, 64, 2); STG_A(An, 64, 3);
        STG_B(Bn, 64, 0); STG_B(Bn, 64, 1);
        for (int kt = 0; kt < 16; ++kt) {
            if (kt < 15) asm volatile("s_waitcnt vmcnt(6)\n\ts_barrier" ::: "memory");
            else         asm volatile("s_waitcnt vmcnt(0)\n\ts_barrier" ::: "memory");
            const int kk2 = (kt + 2) * 64;
            const bool st = (kt < 14);
            bf16x8 af[2][2], bw[4][2];
            #pragma unroll
            for (int i2 = 0; i2 < 2; ++i2) {
                int ra = wro + i2 * 16 + l15;
                af[i2][0] = LDF(Ac, ra, 0); af[i2][1] = LDF(Ac, ra, 1);
            }
            #pragma unroll
            for (int j = 0; j < 4; ++j) {
                int rb = wco + j * 16 + l15;
                bw[j][0] = LDF(Bc, rb, 0); bw[j][1] = LDF(Bc, rb, 1);
            }
            if (st) { STG_A(Af, kk2, 0); STG_A(Af, kk2, 1); STG_B(Bf, kk2, 0); }
            __builtin_amdgcn_s_setprio(1);
            #pragma unroll
            for (int i2 = 0; i2 < 2; ++i2)
                #pragma unroll
                for (int j = 0; j < 4; ++j) {
                    acc[i2][j] = mfma16(af[i2][0], bw[j][0], acc[i2][j]);
                    acc[i2][j] = mfma16(af[i2][1], bw[j][1], acc[i2][j]);
                }
            __builtin_amdgcn_s_setprio(0);
            asm volatile("s_barrier" ::: "memory");
            #pragma unroll
            for (int i2 = 0; i2 < 2; ++i2) {
                int ra = wro + (2 + i2) * 16 + l15;
                af[i2][0] = LDF(Ac, ra, 0); af[i2][1] = LDF(Ac, ra, 1);
            }
            if (st) { STG_A(Af, kk2, 2); STG_A(Af, kk2, 3); STG_B(Bf, kk2, 1); }
            __builtin_amdgcn_s_setprio(1);
            #pragma unroll
            for (int i2 = 0; i2 < 2; ++i2)
                #pragma unroll
                for (int j = 0; j < 4; ++j) {
                    acc[2 + i2][j] = mfma16(af[i2][0], bw[j][0], acc[2 + i2][j]);
                    acc[2 + i2][j] = mfma16(af[i2][1], bw[j][1], acc[2 + i2][j]);
                }
            __builtin_amdgcn_s_setprio(0);
            bf16* tp;
            tp = Ac; Ac = An; An = Af; Af = tp;
            tp = Bc; Bc = Bn; Bn = Bf; Bf = tp;
        }
    }

    #pragma unroll
    for (int i = 0; i < 4; ++i)
        #pragma unroll
        for (int j = 0; j < 4; ++j)
            #pragma unroll
            for (int r = 0; r < 4; ++r) {
                int mg = m0 + wro + i * 16 + quad * 4 + r;
                int ng = n0 + wco + j * 16 + l15;
                out[(size_t)mg * E_ + ng] = acc[i][j][r] + bias[ng];
            }
}

// ---------------------------------------------------------------- launch
extern "C" void kernel_launch(void* const* d_in, const int* in_sizes, int n_in,
                              void* d_out, int out_size, void* d_ws, size_t ws_size,
                              hipStream_t stream) {
    const float* x     = (const float*)d_in[0];   // [B,S,E]
    const float* w_in  = (const float*)d_in[1];   // [3E,E]
    const float* b_in  = (const float*)d_in[2];   // [3E]
    const float* w_out = (const float*)d_in[3];   // [E,E]
    const float* b_out = (const float*)d_in[4];   // [E]
    float* out = (float*)d_out;

    char* ws = (char*)d_ws;
    bf16* Xbf  = (bf16*)ws; ws += (size_t)M_ * E_ * 2;
    bf16* Wqkv = (bf16*)ws; ws += (size_t)N3_ * E_ * 2;
    bf16* Wo   = (bf16*)ws; ws += (size_t)E_ * E_ * 2;
    bf16* QKV  = (bf16*)ws; ws += (size_t)2 * B_ * H_ * S_ * D_ * 2;  // Q,K only
    bf16* Vt   = (bf16*)ws; ws += (size_t)B_ * H_ * S_ * D_ * 2;
    bf16* Obf  = Xbf;   // Xbf dead after gemm_qkv

    cvt_all<<<2048, 256, 0, stream>>>(x, w_in, w_out, Xbf, Wqkv, Wo);

    gemm_qkv<<<dim3(N3_ / 128, M_ / 128), 256, 0, stream>>>(Xbf, Wqkv, b_in, QKV, Vt);

    bf16* Qp = QKV;
    bf16* Kp = QKV + (size_t)B_ * H_ * S_ * D_;

    attn8<<<dim3(8 * B_ * H_), 512, 0, stream>>>(Qp, Kp, Vt, Obf);

    gemm_out<<<dim3(E_ / 128, M_ / 256), 512, 0, stream>>>(Obf, Wo, b_out, out);
}